// Round 3
// baseline (4495.696 us; speedup 1.0000x reference)
//
#include <hip/hip_runtime.h>
#include <math.h>
#include <stdint.h>

#define BB 32
#define TT 2048
#define FF 128
#define HH 512
#define FCC 128
#define QW 8      // workgroups per batch
#define RPW 64    // hidden rows per WG
#define NTH 512   // threads per WG

// LDS pad: +4 words per 64 -> the 8 c-chunk b128 streams hit disjoint banks
__device__ __forceinline__ int hpad(int i) { return i + ((i >> 6) << 2); }

// barrier WITHOUT vmcnt drain: LDS ordering only. Global loads in flight
// (x prefetch, publish store) are NOT drained; compiler auto-waits before use.
__device__ __forceinline__ void barrier_lgkm() {
    asm volatile("s_waitcnt lgkmcnt(0)\n\ts_barrier" ::: "memory");
}

__device__ __forceinline__ float fast_tanh(float z) {
    float ax = fabsf(z);
    float e  = __expf(-2.0f * ax);          // v_exp_f32 path, branchless
    float r  = (1.0f - e) / (1.0f + e);
    return copysignf(r, z);
}

__global__ void ws_zero(uint64_t* g) {
    g[(size_t)blockIdx.x * blockDim.x + threadIdx.x] = 0ull;
}

// grid = 256 blocks (1/CU, co-resident). Batch b = blk&31, slice q = blk>>5
// -> a batch's 8 WGs land on one XCD under round-robin dispatch (perf only).
// Thread (row=tid>>3, c=tid&7): rows q*64+row, cols [c*64,c*64+64) of W_hh
// in 16 NAMED float4 VGPRs. Per step: matvec from LDS h (double-buffered),
// 3 shfl reduce, c==0 publishes tagged (step<<32|value) u64 agent-atomics;
// every thread polls 1 slot, stages h into the other LDS buffer, fused
// scorer dot, ONE lgkm-only barrier.
__global__ __launch_bounds__(NTH, 1)
void rnn_seq(const float* __restrict__ x, const int* __restrict__ lengths,
             const float* __restrict__ W_ih, const float* __restrict__ W_hh,
             const float* __restrict__ b_ih, const float* __restrict__ b_hh,
             const float* __restrict__ W1, const float* __restrict__ b1,
             const float* __restrict__ W2, const float* __restrict__ b2,
             float* __restrict__ out, uint64_t* __restrict__ gbuf)
{
    const int blk = blockIdx.x;
    const int b   = blk & 31;       // batch (same-XCD grouping)
    const int q   = blk >> 5;       // row slice
    const int tid = threadIdx.x;
    const int row = tid >> 3;
    const int c   = tid & 7;
    const int grow = q * RPW + row;
    const int len = lengths[b];

    __shared__ float hsA[HH + 32];
    __shared__ float hsB[HH + 32];
    __shared__ float red[2][8];

    // ---- W_hh slice: 16 named float4s (force VGPR residency) ----
    const float4* wp = (const float4*)(W_hh + (size_t)grow * HH + c * 64);
    float4 ww0 = wp[0],  ww1 = wp[1],  ww2 = wp[2],  ww3 = wp[3];
    float4 ww4 = wp[4],  ww5 = wp[5],  ww6 = wp[6],  ww7 = wp[7];
    float4 ww8 = wp[8],  ww9 = wp[9],  ww10 = wp[10], ww11 = wp[11];
    float4 ww12 = wp[12], ww13 = wp[13], ww14 = wp[14], ww15 = wp[15];

    const float4* wip = (const float4*)(W_ih + grow * FF + c * 16);
    float4 wi0 = wip[0], wi1 = wip[1], wi2 = wip[2], wi3 = wip[3];

    const float bias_r = b_ih[grow] + b_hh[grow];

    // fused scorer: wv[tid] = sum_f W2[f] * W1[f, tid];  c = W2@b1 + b2
    float wv = 0.0f;
    #pragma unroll 8
    for (int f = 0; f < FCC; ++f) wv += W2[f] * W1[f * HH + tid];
    float cconst = b2[0];
    #pragma unroll 8
    for (int f = 0; f < FCC; ++f) cconst += W2[f] * b1[f];

    hsA[hpad(tid)] = 0.0f;

    const float* xb = x + (size_t)b * TT * FF + c * 16;
    float4 ra0, ra1, ra2, ra3, rb0, rb1, rb2, rb3;
    { const float4* p = (const float4*)(xb);                 ra0 = p[0]; ra1 = p[1]; ra2 = p[2]; ra3 = p[3]; }
    { const float4* p = (const float4*)(xb + (size_t)FF);    rb0 = p[0]; rb1 = p[1]; rb2 = p[2]; rb3 = p[3]; }

    uint64_t* slot0 = gbuf + (size_t)b * HH;
    uint64_t* slot1 = gbuf + (size_t)(BB + b) * HH;

    float xaccA = wi0.x*ra0.x + wi0.y*ra0.y + wi0.z*ra0.z + wi0.w*ra0.w
                + wi1.x*ra1.x + wi1.y*ra1.y + wi1.z*ra1.z + wi1.w*ra1.w
                + wi2.x*ra2.x + wi2.y*ra2.y + wi2.z*ra2.z + wi2.w*ra2.w
                + wi3.x*ra3.x + wi3.y*ra3.y + wi3.z*ra3.z + wi3.w*ra3.w;
    float xaccB = 0.0f;

    int count = 0;
    __syncthreads();   // hsA init visible (one-time full barrier)

#define MV4(K) { float4 hk = hq[K]; \
    a0 += ww##K.x * hk.x; a1 += ww##K.y * hk.y; \
    a2 += ww##K.z * hk.z; a3 += ww##K.w * hk.w; }

#define STEP(I, HCUR, HNXT, XCUR, XNXT, RN0,RN1,RN2,RN3, RL0,RL1,RL2,RL3)       \
  {                                                                             \
    const float4* hq = (const float4*)(HCUR + c * 68);                          \
    float a0 = XCUR, a1 = 0.f, a2 = 0.f, a3 = 0.f;                              \
    MV4(0) MV4(1) MV4(2) MV4(3) MV4(4) MV4(5) MV4(6) MV4(7)                     \
    MV4(8) MV4(9) MV4(10) MV4(11) MV4(12) MV4(13) MV4(14) MV4(15)               \
    float acc = (a0 + a1) + (a2 + a3);                                          \
    acc += __shfl_xor(acc, 1);                                                  \
    acc += __shfl_xor(acc, 2);                                                  \
    acc += __shfl_xor(acc, 4);                                                  \
    uint64_t* sw = ((I) & 1) ? slot1 : slot0;                                   \
    if (c == 0) {                                                               \
      float hn = fast_tanh(acc + bias_r);                                       \
      uint64_t pk = ((uint64_t)(uint32_t)((I) + 1) << 32) |                     \
                    (uint64_t)__float_as_uint(hn);                              \
      __hip_atomic_store(&sw[grow], pk, __ATOMIC_RELAXED,                       \
                         __HIP_MEMORY_SCOPE_AGENT);                             \
    }                                                                           \
    /* W_ih . x_{I+1} during the publish-visibility window */                   \
    XNXT = wi0.x*RN0.x + wi0.y*RN0.y + wi0.z*RN0.z + wi0.w*RN0.w                \
         + wi1.x*RN1.x + wi1.y*RN1.y + wi1.z*RN1.z + wi1.w*RN1.w                \
         + wi2.x*RN2.x + wi2.y*RN2.y + wi2.z*RN2.z + wi2.w*RN2.w                \
         + wi3.x*RN3.x + wi3.y*RN3.y + wi3.z*RN3.z + wi3.w*RN3.w;               \
    { int tp = (I) + 2;                                                         \
      if (tp < len) { const float4* p = (const float4*)(xb + (size_t)tp * FF);  \
        RL0 = p[0]; RL1 = p[1]; RL2 = p[2]; RL3 = p[3]; } }                     \
    {                                                                           \
      const uint64_t tg = (uint64_t)(uint32_t)((I) + 1);                        \
      uint64_t u;                                                               \
      do { u = __hip_atomic_load(&sw[tid], __ATOMIC_RELAXED,                    \
                                 __HIP_MEMORY_SCOPE_AGENT); }                   \
      while ((u >> 32) != tg);                                                  \
      float hv = __uint_as_float((uint32_t)u);                                  \
      HNXT[hpad(tid)] = hv;                                                     \
      float p2 = hv * wv;                                                       \
      p2 += __shfl_xor(p2, 1);  p2 += __shfl_xor(p2, 2);                        \
      p2 += __shfl_xor(p2, 4);  p2 += __shfl_xor(p2, 8);                        \
      p2 += __shfl_xor(p2, 16); p2 += __shfl_xor(p2, 32);                       \
      if ((tid & 63) == 0) red[(I) & 1][tid >> 6] = p2;                         \
    }                                                                           \
    barrier_lgkm();                                                             \
    if (tid == 0) {                                                             \
      float s = cconst;                                                         \
      _Pragma("unroll")                                                         \
      for (int w = 0; w < 8; ++w) s += red[(I) & 1][w];                         \
      if (s > 0.0f) ++count;                                                    \
    }                                                                           \
  }

    int i = 0;
    for (;;) {
        STEP(i, hsA, hsB, xaccA, xaccB, rb0,rb1,rb2,rb3, ra0,ra1,ra2,ra3);
        if (++i >= len) break;
        STEP(i, hsB, hsA, xaccB, xaccA, ra0,ra1,ra2,ra3, rb0,rb1,rb2,rb3);
        if (++i >= len) break;
    }

    if (q == 0) {
        const float* hf = (len & 1) ? hsB : hsA;
        out[BB + b * HH + tid] = hf[hpad(tid)];
        if (tid == 0) out[b] = (float)count;
    }
}

extern "C" void kernel_launch(void* const* d_in, const int* in_sizes, int n_in,
                              void* d_out, int out_size, void* d_ws, size_t ws_size,
                              hipStream_t stream) {
    const float* x    = (const float*)d_in[0];
    const int*   lens = (const int*)d_in[1];
    const float* W_ih = (const float*)d_in[2];
    const float* W_hh = (const float*)d_in[3];
    const float* b_ih = (const float*)d_in[4];
    const float* b_hh = (const float*)d_in[5];
    const float* W1   = (const float*)d_in[6];
    const float* b1   = (const float*)d_in[7];
    const float* W2   = (const float*)d_in[8];
    const float* b2   = (const float*)d_in[9];
    float* out = (float*)d_out;
    uint64_t* gbuf = (uint64_t*)d_ws;   // 2 * 32 * 512 u64 = 256 KB

    ws_zero<<<dim3((2 * BB * HH) / 256), dim3(256), 0, stream>>>(gbuf);
    rnn_seq<<<dim3(BB * QW), dim3(NTH), 0, stream>>>(
        x, lens, W_ih, W_hh, b_ih, b_hh, W1, b1, W2, b2, out, gbuf);
}

// Round 4
// 3685.672 us; speedup vs baseline: 1.2198x; 1.2198x over previous
//
#include <hip/hip_runtime.h>
#include <math.h>
#include <stdint.h>

#define BB 32
#define TT 2048
#define FF 128
#define HH 512
#define FCC 128
#define QW 8      // workgroups per batch
#define RPW 64    // hidden rows per WG
#define NTH 512   // threads per WG

// LDS pad: +4 words per 64 -> the 8 c-chunk b128 streams hit disjoint banks
__device__ __forceinline__ int hpad(int i) { return i + ((i >> 6) << 2); }

// barrier WITHOUT vmcnt drain: LDS ordering only. Global ops in flight
// (x prefetch, publish store) are NOT drained; compiler auto-waits before use.
__device__ __forceinline__ void barrier_lgkm() {
    asm volatile("s_waitcnt lgkmcnt(0)\n\ts_barrier" ::: "memory");
}

__global__ void ws_zero(uint64_t* g) {
    g[(size_t)blockIdx.x * blockDim.x + threadIdx.x] = 0ull;
}

// grid = 256 blocks (1/CU, co-resident). b = blk>>3, q = blk&7 (round-2 map).
// Thread (row=tid>>3, c=tid&7): rows q*64+row, cols [c*64,c*64+64) of W_hh in
// 16 named float4 VGPRs. Per step:
//   - scorer (q==0, tid<128): score h_i from LDS hcur, CONCURRENT with matvec
//   - matvec from hcur + 3 shfl reduce
//   - c==0 lanes: tanh, write own h straight to LDS hnxt + tagged u64 publish
//   - pollers tid<128 (skipping own WG's 16-thread range): 4 pipelined tagged
//     loads per iteration, stage peers' h into hnxt
//   - ONE lgkm-only barrier; swap buffers
__global__ __launch_bounds__(NTH, 1)
void rnn_seq(const float* __restrict__ x, const int* __restrict__ lengths,
             const float* __restrict__ W_ih, const float* __restrict__ W_hh,
             const float* __restrict__ b_ih, const float* __restrict__ b_hh,
             const float* __restrict__ W1, const float* __restrict__ b1,
             const float* __restrict__ W2, const float* __restrict__ b2,
             float* __restrict__ out, uint64_t* __restrict__ gbuf)
{
    const int blk = blockIdx.x;
    const int b   = blk >> 3;       // batch
    const int q   = blk & 7;        // row slice
    const int tid = threadIdx.x;
    const int row = tid >> 3;
    const int c   = tid & 7;
    const int grow = q * RPW + row;
    const int len = lengths[b];

    __shared__ float hsA[HH + 32];
    __shared__ float hsB[HH + 32];
    __shared__ float red[2][2];

    // ---- W_hh slice: 16 named float4s (VGPR/AGPR-resident) ----
    const float4* wp = (const float4*)(W_hh + (size_t)grow * HH + c * 64);
    float4 ww0 = wp[0],  ww1 = wp[1],  ww2 = wp[2],  ww3 = wp[3];
    float4 ww4 = wp[4],  ww5 = wp[5],  ww6 = wp[6],  ww7 = wp[7];
    float4 ww8 = wp[8],  ww9 = wp[9],  ww10 = wp[10], ww11 = wp[11];
    float4 ww12 = wp[12], ww13 = wp[13], ww14 = wp[14], ww15 = wp[15];

    const float4* wip = (const float4*)(W_ih + grow * FF + c * 16);
    float4 wi0 = wip[0], wi1 = wip[1], wi2 = wip[2], wi3 = wip[3];

    const float bias_r = b_ih[grow] + b_hh[grow];

    // fused scorer: wvr = (W2 @ W1)[4t..4t+3];  cconst = W2@b1 + b2
    float4 wvr = make_float4(0.f, 0.f, 0.f, 0.f);
    if (tid < 128) {
        for (int f = 0; f < FCC; ++f) {
            float w2 = W2[f];
            const float* w1 = W1 + f * HH + tid * 4;
            wvr.x += w2 * w1[0]; wvr.y += w2 * w1[1];
            wvr.z += w2 * w1[2]; wvr.w += w2 * w1[3];
        }
    }
    float cconst = 0.f;
    if (q == 0 && tid == 0) {
        float a = 0.f;
        for (int f = 0; f < FCC; ++f) a += W2[f] * b1[f];
        cconst = a + b2[0];
    }

    hsA[hpad(tid)] = 0.0f;
    __syncthreads();                 // one-time full barrier (hsA init)

    const float* xb = x + (size_t)b * TT * FF + c * 16;
    float4 rc0, rc1, rc2, rc3, rn0, rn1, rn2, rn3;
    { const float4* p = (const float4*)(xb);              rc0 = p[0]; rc1 = p[1]; rc2 = p[2]; rc3 = p[3]; }
    { const float4* p = (const float4*)(xb + (size_t)FF); rn0 = p[0]; rn1 = p[1]; rn2 = p[2]; rn3 = p[3]; }

    uint64_t* slot0 = gbuf + (size_t)b * HH;
    uint64_t* slot1 = gbuf + (size_t)(BB + b) * HH;

    float* hcur = hsA;
    float* hnxt = hsB;
    const int sc_off = tid * 4 + ((tid >> 4) << 2);   // hpad(4*tid)
    const bool is_poller = (tid < 128) && ((tid >> 4) != q);
    const bool is_scorer = (q == 0) && (tid < 128);

    int count = 0;

#define MV4(K) { float4 hk = hq[K]; \
    a0 += ww##K.x * hk.x; a1 += ww##K.y * hk.y; \
    a2 += ww##K.z * hk.z; a3 += ww##K.w * hk.w; }

    for (int i = 0; i < len; ++i) {
        // ---- deferred scorer on h_i (already synced in hcur); overlaps matvec
        if (is_scorer && i > 0) {
            float4 hv = *(const float4*)(hcur + sc_off);
            float p2 = hv.x * wvr.x + hv.y * wvr.y + hv.z * wvr.z + hv.w * wvr.w;
            p2 += __shfl_xor(p2, 1);  p2 += __shfl_xor(p2, 2);
            p2 += __shfl_xor(p2, 4);  p2 += __shfl_xor(p2, 8);
            p2 += __shfl_xor(p2, 16); p2 += __shfl_xor(p2, 32);
            if ((tid & 63) == 0) red[i & 1][tid >> 6] = p2;
        }

        // ---- matvec: acc = W_ih[grow,chunk].x_i + W_hh[grow,chunk].h_i
        const float4* hq = (const float4*)(hcur + c * 68);
        float a0, a1, a2, a3;
        a0 = wi0.x*rc0.x + wi0.y*rc0.y + wi0.z*rc0.z + wi0.w*rc0.w;
        a1 = wi1.x*rc1.x + wi1.y*rc1.y + wi1.z*rc1.z + wi1.w*rc1.w;
        a2 = wi2.x*rc2.x + wi2.y*rc2.y + wi2.z*rc2.z + wi2.w*rc2.w;
        a3 = wi3.x*rc3.x + wi3.y*rc3.y + wi3.z*rc3.z + wi3.w*rc3.w;
        MV4(0)  MV4(1)  MV4(2)  MV4(3)  MV4(4)  MV4(5)  MV4(6)  MV4(7)
        MV4(8)  MV4(9)  MV4(10) MV4(11) MV4(12) MV4(13) MV4(14) MV4(15)
        float acc = (a0 + a1) + (a2 + a3);
        acc += __shfl_xor(acc, 1);
        acc += __shfl_xor(acc, 2);
        acc += __shfl_xor(acc, 4);

        uint64_t* sw = (i & 1) ? slot1 : slot0;
        if (c == 0) {
            float hn = tanhf(acc + bias_r);
            hnxt[hpad(grow)] = hn;                     // own slice -> LDS direct
            uint64_t pk = ((uint64_t)(uint32_t)(i + 1) << 32) |
                          (uint64_t)__float_as_uint(hn);
            __hip_atomic_store(&sw[grow], pk, __ATOMIC_RELAXED,
                               __HIP_MEMORY_SCOPE_AGENT);
        }

        // ---- rotate x prefetch (off critical path; no vmcnt drain at barrier)
        rc0 = rn0; rc1 = rn1; rc2 = rn2; rc3 = rn3;
        if (i + 2 < len) {
            const float4* p = (const float4*)(xb + (size_t)(i + 2) * FF);
            rn0 = p[0]; rn1 = p[1]; rn2 = p[2]; rn3 = p[3];
        }

        // ---- poll peers' slices: 4 pipelined tagged loads per iteration
        if (is_poller) {
            const uint64_t tg = (uint64_t)(uint32_t)(i + 1);
            uint64_t* pr = sw + tid * 4;
            uint64_t u0, u1, u2, u3;
            do {
                u0 = __hip_atomic_load(pr + 0, __ATOMIC_RELAXED, __HIP_MEMORY_SCOPE_AGENT);
                u1 = __hip_atomic_load(pr + 1, __ATOMIC_RELAXED, __HIP_MEMORY_SCOPE_AGENT);
                u2 = __hip_atomic_load(pr + 2, __ATOMIC_RELAXED, __HIP_MEMORY_SCOPE_AGENT);
                u3 = __hip_atomic_load(pr + 3, __ATOMIC_RELAXED, __HIP_MEMORY_SCOPE_AGENT);
            } while ((u0 >> 32) != tg || (u1 >> 32) != tg ||
                     (u2 >> 32) != tg || (u3 >> 32) != tg);
            float4 hv = make_float4(__uint_as_float((uint32_t)u0),
                                    __uint_as_float((uint32_t)u1),
                                    __uint_as_float((uint32_t)u2),
                                    __uint_as_float((uint32_t)u3));
            *(float4*)(hnxt + sc_off) = hv;
        }

        barrier_lgkm();

        if (is_scorer && tid == 0 && i > 0) {
            float s = cconst + red[i & 1][0] + red[i & 1][1];
            if (s > 0.0f) ++count;
        }
        float* t = hcur; hcur = hnxt; hnxt = t;
    }

    // ---- final score: h_len is in hcur (post-swap) ----
    if (q == 0) {
        const int fi = len & 1;   // disjoint from red[(len-1)&1] read last iter
        if (tid < 128) {
            float4 hv = *(const float4*)(hcur + sc_off);
            float p2 = hv.x * wvr.x + hv.y * wvr.y + hv.z * wvr.z + hv.w * wvr.w;
            p2 += __shfl_xor(p2, 1);  p2 += __shfl_xor(p2, 2);
            p2 += __shfl_xor(p2, 4);  p2 += __shfl_xor(p2, 8);
            p2 += __shfl_xor(p2, 16); p2 += __shfl_xor(p2, 32);
            if ((tid & 63) == 0) red[fi][tid >> 6] = p2;
        }
        barrier_lgkm();
        if (tid == 0) {
            float s = cconst + red[fi][0] + red[fi][1];
            if (s > 0.0f) ++count;
            out[b] = (float)count;
        }
        out[BB + b * HH + tid] = hcur[hpad(tid)];
    }
}

extern "C" void kernel_launch(void* const* d_in, const int* in_sizes, int n_in,
                              void* d_out, int out_size, void* d_ws, size_t ws_size,
                              hipStream_t stream) {
    const float* x    = (const float*)d_in[0];
    const int*   lens = (const int*)d_in[1];
    const float* W_ih = (const float*)d_in[2];
    const float* W_hh = (const float*)d_in[3];
    const float* b_ih = (const float*)d_in[4];
    const float* b_hh = (const float*)d_in[5];
    const float* W1   = (const float*)d_in[6];
    const float* b1   = (const float*)d_in[7];
    const float* W2   = (const float*)d_in[8];
    const float* b2   = (const float*)d_in[9];
    float* out = (float*)d_out;
    uint64_t* gbuf = (uint64_t*)d_ws;   // 2 * 32 * 512 u64 = 256 KB

    ws_zero<<<dim3((2 * BB * HH) / 256), dim3(256), 0, stream>>>(gbuf);
    rnn_seq<<<dim3(BB * QW), dim3(NTH), 0, stream>>>(
        x, lens, W_ih, W_hh, b_ih, b_hh, W1, b1, W2, b2, out, gbuf);
}